// Round 6
// baseline (43603.564 us; speedup 1.0000x reference)
//
#include <hip/hip_runtime.h>
#include <math.h>

// ============================================================================
// AR_Transcriber round 6.
// r5 finding: LSTM was bound by the h-broadcast done with per-lane agent-scope
// ATOMIC 8B loads (~4.1M uncoalesced coherence-fabric requests/step) -- not by
// the barrier. Fix: h/prev exchange uses NORMAL coalesced float4 loads/stores
// (L2-cached; 24 blocks/XCD share one 49KB L3 fetch), with __threadfence()
// (agent wb+inv) inside the barrier for cross-XCD visibility. This is safe now
// because weights are register-resident (r4) -- L2 invalidation no longer
// evicts anything expensive. Barrier stays hierarchical (r5).
// ============================================================================

typedef unsigned long long ull;

#define ACO_FL 6266880ull  // 8160*768

__device__ __forceinline__ float sigf(float x) { return 1.0f / (1.0f + expf(-x)); }

// Hierarchical grid barrier with cache maintenance.
// bar layout (unsigned): [0..127] 8 arrival counters 64B apart; [128] release.
__device__ __forceinline__ void gbar(unsigned* bar, unsigned nb, unsigned NG) {
  __syncthreads();
  if (threadIdx.x == 0) {
    __threadfence();  // release: waitcnt + L2 writeback (our h stores -> L3)
    __hip_atomic_fetch_add(bar + (blockIdx.x & 7) * 16, 1u,
                           __ATOMIC_RELAXED, __HIP_MEMORY_SCOPE_AGENT);
    unsigned* rel = bar + 128;
    if (blockIdx.x == 0) {
      const unsigned target = nb * NG;
      for (;;) {
        unsigned s0 = 0;
#pragma unroll
        for (int i = 0; i < 8; ++i)
          s0 += __hip_atomic_load(bar + i * 16, __ATOMIC_RELAXED,
                                  __HIP_MEMORY_SCOPE_AGENT);
        if (s0 >= target) break;
        __builtin_amdgcn_s_sleep(1);
      }
      __hip_atomic_store(rel, nb, __ATOMIC_RELAXED, __HIP_MEMORY_SCOPE_AGENT);
    } else {
      while (__hip_atomic_load(rel, __ATOMIC_RELAXED,
                               __HIP_MEMORY_SCOPE_AGENT) < nb) {
        __builtin_amdgcn_s_sleep(1);
      }
    }
    __threadfence();  // acquire: invalidate L1/L2 so fresh h is re-fetched
  }
  __syncthreads();
}

__device__ __forceinline__ float red16(float v) {
  v += __shfl_xor(v, 1, 16);
  v += __shfl_xor(v, 2, 16);
  v += __shfl_xor(v, 4, 16);
  v += __shfl_xor(v, 8, 16);
  return v;
}

// 48-FMA chunk dot: weights from VGPR array W, data from LDS pointer PTR.
#define CDOT48(W, PTR, RES) do {                                              \
  const float* _p = (PTR);                                                    \
  float _a0 = 0.f, _a1 = 0.f, _a2 = 0.f, _a3 = 0.f;                           \
  _Pragma("unroll")                                                           \
  for (int _i = 0; _i < 48; _i += 16) {                                       \
    float4 _v0 = *(const float4*)(_p + _i);                                   \
    float4 _v1 = *(const float4*)(_p + _i + 4);                               \
    float4 _v2 = *(const float4*)(_p + _i + 8);                               \
    float4 _v3 = *(const float4*)(_p + _i + 12);                              \
    _a0 = fmaf((W)[_i + 0], _v0.x, _a0); _a0 = fmaf((W)[_i + 1], _v0.y, _a0); \
    _a0 = fmaf((W)[_i + 2], _v0.z, _a0); _a0 = fmaf((W)[_i + 3], _v0.w, _a0); \
    _a1 = fmaf((W)[_i + 4], _v1.x, _a1); _a1 = fmaf((W)[_i + 5], _v1.y, _a1); \
    _a1 = fmaf((W)[_i + 6], _v1.z, _a1); _a1 = fmaf((W)[_i + 7], _v1.w, _a1); \
    _a2 = fmaf((W)[_i + 8], _v2.x, _a2); _a2 = fmaf((W)[_i + 9], _v2.y, _a2); \
    _a2 = fmaf((W)[_i +10], _v2.z, _a2); _a2 = fmaf((W)[_i +11], _v2.w, _a2); \
    _a3 = fmaf((W)[_i +12], _v3.x, _a3); _a3 = fmaf((W)[_i +13], _v3.y, _a3); \
    _a3 = fmaf((W)[_i +14], _v3.z, _a3); _a3 = fmaf((W)[_i +15], _v3.w, _a3); \
  }                                                                           \
  RES = (_a0 + _a1) + (_a2 + _a3);                                            \
} while (0)

// Stage one h buffer (float [16][768], b-major) into hs chunked [s][b][48].
// Coalesced: thread tid loads float4 at element tid*4 (+1024/iter, 12 iters).
#define STAGE_H(SRC) do {                                                     \
  _Pragma("unroll")                                                           \
  for (int _e = tid * 4; _e < 12288; _e += 1024) {                            \
    float4 _v = *(const float4*)((SRC) + _e);                                 \
    int _b = _e / 768, _u = _e - _b * 768;                                    \
    int _s = _u / 48, _k = _u - _s * 48;                                      \
    *(float4*)(hs + _s * 772 + _b * 48 + _k) = _v;                            \
  }                                                                           \
} while (0)

// ---------------------------------------------------------------------------
// K1: fused conv1+bn1+relu -> conv2+bn2+relu -> pool(1,2). (unchanged)
// ---------------------------------------------------------------------------
__global__ __launch_bounds__(256) void conv12_kernel(
    const float* __restrict__ mel,
    const float* __restrict__ c1w, const float* __restrict__ c1b,
    const float* __restrict__ bn1g, const float* __restrict__ bn1b,
    const float* __restrict__ bn1m, const float* __restrict__ bn1v,
    const float* __restrict__ c2w, const float* __restrict__ c2b,
    const float* __restrict__ bn2g, const float* __restrict__ bn2b,
    const float* __restrict__ bn2m, const float* __restrict__ bn2v,
    float* __restrict__ A, int b0)
{
  __shared__ float melS[5 * 232];
  __shared__ float x1S[12 * 3 * 232];
  __shared__ float wS[48 * 12 * 9];
  const int tid = threadIdx.x;
  const int bl = blockIdx.x >> 9;
  const int b = b0 + bl;
  const int t = blockIdx.x & 511;

  for (int idx = tid; idx < 5 * 232; idx += 256) {
    int rr = idx / 232, cc = idx - rr * 232;
    int r = t - 2 + rr, w = cc - 1;
    float v = 0.f;
    if (r >= 0 && r < 512 && w >= 0 && w < 229) v = mel[(b * 512 + r) * 229 + w];
    melS[idx] = v;
  }

  float accA[22], accB[22];
#pragma unroll
  for (int i = 0; i < 22; ++i) { accA[i] = 0.f; accB[i] = 0.f; }
  __syncthreads();

  for (int icc = 0; icc < 4; ++icc) {
    if (icc) __syncthreads();
    for (int idx = tid; idx < 12 * 3 * 232; idx += 256) {
      int cl = idx / (3 * 232);
      int rem = idx - cl * (3 * 232);
      int rr = rem / 232, cc = rem - rr * 232;
      int c = icc * 12 + cl;
      int r1 = t - 1 + rr, w = cc - 1;
      float v = 0.f;
      if (r1 >= 0 && r1 < 512 && w >= 0 && w < 229) {
        const float* cw = c1w + c * 9;
        const float* m0 = melS + rr * 232 + cc - 1;
        float s = m0[0] * cw[0] + m0[1] * cw[1] + m0[2] * cw[2]
                + m0[232] * cw[3] + m0[233] * cw[4] + m0[234] * cw[5]
                + m0[464] * cw[6] + m0[465] * cw[7] + m0[466] * cw[8];
        s += c1b[c];
        float sc = bn1g[c] * rsqrtf(bn1v[c] + 1e-5f);
        v = fmaxf(s * sc + (bn1b[c] - bn1m[c] * sc), 0.f);
      }
      x1S[idx] = v;
    }
    for (int idx = tid; idx < 48 * 12 * 9; idx += 256) {
      int oc = idx / 108, rem = idx - oc * 108;
      wS[idx] = c2w[(oc * 48 + icc * 12) * 9 + rem];
    }
    __syncthreads();
    for (int i = 0; i < 22; ++i) {
      int oidx = tid + i * 256;
      if (oidx >= 5472) break;
      int oc = oidx / 114, wp = oidx - oc * 114;
      int w0 = 2 * wp;
      float a0 = accA[i], a1 = accB[i];
      const float* wp9 = wS + oc * 108;
      for (int icl = 0; icl < 12; ++icl) {
#pragma unroll
        for (int a = 0; a < 3; ++a) {
          const float* xr = x1S + (icl * 3 + a) * 232 + w0;
          float x0 = xr[0], x1 = xr[1], x2 = xr[2], x3 = xr[3];
          float wA = wp9[icl * 9 + a * 3 + 0];
          float wB = wp9[icl * 9 + a * 3 + 1];
          float wC = wp9[icl * 9 + a * 3 + 2];
          a0 = fmaf(x0, wA, a0); a0 = fmaf(x1, wB, a0); a0 = fmaf(x2, wC, a0);
          a1 = fmaf(x1, wA, a1); a1 = fmaf(x2, wB, a1); a1 = fmaf(x3, wC, a1);
        }
      }
      accA[i] = a0; accB[i] = a1;
    }
  }
  for (int i = 0; i < 22; ++i) {
    int oidx = tid + i * 256;
    if (oidx >= 5472) break;
    int oc = oidx / 114, wp = oidx - oc * 114;
    float sc = bn2g[oc] * rsqrtf(bn2v[oc] + 1e-5f);
    float sh = bn2b[oc] - bn2m[oc] * sc;
    float v0 = fmaxf((accA[i] + c2b[oc]) * sc + sh, 0.f);
    float v1 = fmaxf((accB[i] + c2b[oc]) * sc + sh, 0.f);
    A[((bl * 48 + oc) * 512 + t) * 114 + wp] = fmaxf(v0, v1);
  }
}

// ---------------------------------------------------------------------------
// K2: conv3+bn3+relu+pool(1,2); GEMM-ready output. (unchanged)
// ---------------------------------------------------------------------------
__global__ __launch_bounds__(256) void conv3_kernel(
    const float* __restrict__ A,
    const float* __restrict__ c3w, const float* __restrict__ c3b,
    const float* __restrict__ bn3g, const float* __restrict__ bn3b,
    const float* __restrict__ bn3m, const float* __restrict__ bn3v,
    float* __restrict__ Bf)
{
  __shared__ float aS[16 * 3 * 116];
  __shared__ float wS[48 * 16 * 9];
  const int tid = threadIdx.x;
  const int bl = blockIdx.x / 510;
  const int t = blockIdx.x - bl * 510;

  for (int ocg = 0; ocg < 2; ++ocg) {
    float accA[11], accB[11];
#pragma unroll
    for (int i = 0; i < 11; ++i) { accA[i] = 0.f; accB[i] = 0.f; }
    for (int icc = 0; icc < 3; ++icc) {
      __syncthreads();
      for (int idx = tid; idx < 16 * 3 * 116; idx += 256) {
        int cl = idx / 348, rem = idx - cl * 348;
        int rr = rem / 116, cc = rem - rr * 116;
        int w = cc - 1;
        float v = 0.f;
        if (w >= 0 && w < 114) v = A[((bl * 48 + icc * 16 + cl) * 512 + t + rr) * 114 + w];
        aS[idx] = v;
      }
      for (int idx = tid; idx < 48 * 16 * 9; idx += 256) {
        int ocl = idx / 144, rem = idx - ocl * 144;
        wS[idx] = c3w[((ocg * 48 + ocl) * 48 + icc * 16) * 9 + rem];
      }
      __syncthreads();
      for (int i = 0; i < 11; ++i) {
        int oidx = tid + i * 256;
        if (oidx >= 2736) break;
        int ocl = oidx / 57, wp = oidx - ocl * 57;
        int w0 = 2 * wp;
        float a0 = accA[i], a1 = accB[i];
        const float* wb = wS + ocl * 144;
        for (int icl = 0; icl < 16; ++icl) {
#pragma unroll
          for (int a = 0; a < 3; ++a) {
            const float* xr = aS + (icl * 3 + a) * 116 + w0;
            float x0 = xr[0], x1 = xr[1], x2 = xr[2], x3 = xr[3];
            float wA = wb[icl * 9 + a * 3 + 0];
            float wB = wb[icl * 9 + a * 3 + 1];
            float wC = wb[icl * 9 + a * 3 + 2];
            a0 = fmaf(x0, wA, a0); a0 = fmaf(x1, wB, a0); a0 = fmaf(x2, wC, a0);
            a1 = fmaf(x1, wA, a1); a1 = fmaf(x2, wB, a1); a1 = fmaf(x3, wC, a1);
          }
        }
        accA[i] = a0; accB[i] = a1;
      }
    }
    for (int i = 0; i < 11; ++i) {
      int oidx = tid + i * 256;
      if (oidx >= 2736) break;
      int ocl = oidx / 57, wp = oidx - ocl * 57;
      int oc = ocg * 48 + ocl;
      float sc = bn3g[oc] * rsqrtf(bn3v[oc] + 1e-5f);
      float sh = bn3b[oc] - bn3m[oc] * sc;
      float v0 = fmaxf((accA[i] + c3b[oc]) * sc + sh, 0.f);
      float v1 = fmaxf((accB[i] + c3b[oc]) * sc + sh, 0.f);
      Bf[(size_t)(bl * 510 + t) * 5472 + oc * 57 + wp] = fmaxf(v0, v1);
    }
  }
}

// ---------------------------------------------------------------------------
// K3: fp32 NT GEMM  C[M,N] = A * B^T + bias. (FC only)
// ---------------------------------------------------------------------------
__global__ __launch_bounds__(256) void gemm_nt(
    const float* __restrict__ Am, const float* __restrict__ Bm,
    const float* __restrict__ bias, float* __restrict__ C,
    int M, int N, int K, int lda, int ldb, int ldc)
{
  __shared__ float As[64 * 33];
  __shared__ float Bs[64 * 33];
  const int tid = threadIdx.x;
  const int m0 = blockIdx.x * 64, n0 = blockIdx.y * 64;
  const int tx = tid & 15, ty = tid >> 4;
  const int kq = (tid & 7) * 4, rw = tid >> 3;
  float acc[4][4];
#pragma unroll
  for (int i = 0; i < 4; ++i)
#pragma unroll
    for (int j = 0; j < 4; ++j) acc[i][j] = 0.f;

  for (int k0 = 0; k0 < K; k0 += 32) {
    int m1 = m0 + rw, m2 = m1 + 32;
    float4 va = make_float4(0.f, 0.f, 0.f, 0.f), vb = va;
    if (m1 < M) va = *(const float4*)(Am + (size_t)m1 * lda + k0 + kq);
    if (m2 < M) vb = *(const float4*)(Am + (size_t)m2 * lda + k0 + kq);
    float4 wa = *(const float4*)(Bm + (size_t)(n0 + rw) * ldb + k0 + kq);
    float4 wb = *(const float4*)(Bm + (size_t)(n0 + rw + 32) * ldb + k0 + kq);
    As[rw * 33 + kq + 0] = va.x; As[rw * 33 + kq + 1] = va.y;
    As[rw * 33 + kq + 2] = va.z; As[rw * 33 + kq + 3] = va.w;
    As[(rw + 32) * 33 + kq + 0] = vb.x; As[(rw + 32) * 33 + kq + 1] = vb.y;
    As[(rw + 32) * 33 + kq + 2] = vb.z; As[(rw + 32) * 33 + kq + 3] = vb.w;
    Bs[rw * 33 + kq + 0] = wa.x; Bs[rw * 33 + kq + 1] = wa.y;
    Bs[rw * 33 + kq + 2] = wa.z; Bs[rw * 33 + kq + 3] = wa.w;
    Bs[(rw + 32) * 33 + kq + 0] = wb.x; Bs[(rw + 32) * 33 + kq + 1] = wb.y;
    Bs[(rw + 32) * 33 + kq + 2] = wb.z; Bs[(rw + 32) * 33 + kq + 3] = wb.w;
    __syncthreads();
#pragma unroll 8
    for (int k = 0; k < 32; ++k) {
      float av[4], bv[4];
#pragma unroll
      for (int i = 0; i < 4; ++i) av[i] = As[(ty * 4 + i) * 33 + k];
#pragma unroll
      for (int j = 0; j < 4; ++j) bv[j] = Bs[(tx * 4 + j) * 33 + k];
#pragma unroll
      for (int i = 0; i < 4; ++i)
#pragma unroll
        for (int j = 0; j < 4; ++j) acc[i][j] = fmaf(av[i], bv[j], acc[i][j]);
    }
    __syncthreads();
  }
#pragma unroll
  for (int i = 0; i < 4; ++i) {
    int m = m0 + ty * 4 + i;
    if (m >= M) continue;
#pragma unroll
    for (int j = 0; j < 4; ++j) {
      int n = n0 + tx * 4 + j;
      C[(size_t)m * ldc + n] = acc[i][j] + bias[n];
    }
  }
}

// ---------------------------------------------------------------------------
__global__ void init_state(float* __restrict__ h1g, float* __restrict__ h2g,
                           unsigned* __restrict__ bar) {
  int gid = blockIdx.x * 256 + threadIdx.x;
  if (gid < 24576) { h1g[gid] = 0.f; h2g[gid] = 0.f; }
  if (gid < 160)
    __hip_atomic_store(bar + gid, 0u, __ATOMIC_RELAXED, __HIP_MEMORY_SCOPE_AGENT);
}

// ---------------------------------------------------------------------------
// K6: persistent LSTM, register-resident weights; h exchange via normal
// cached loads/stores + barrier fences.
// ---------------------------------------------------------------------------
__global__ __launch_bounds__(256, 1) void lstm_kernel(
    const float* __restrict__ aco,   // [16][510][768]
    const float* __restrict__ whh0,  // [3072][768]
    const float* __restrict__ wih0,  // [3072][944]
    const float* __restrict__ wih1,  // [3072][768]
    const float* __restrict__ whh1,  // [3072][768]
    const float* __restrict__ bih0, const float* __restrict__ bhh0,
    const float* __restrict__ bih1, const float* __restrict__ bhh1,
    const float* __restrict__ pw,    // [440][768]
    const float* __restrict__ pb,
    const float* __restrict__ emb,   // [5][2]
    float* __restrict__ h1g,         // [2][16][768] b-major
    float* __restrict__ h2g,
    float* __restrict__ prevp,       // [16][176] prev embeddings
    unsigned* __restrict__ bar,
    float* __restrict__ out)         // [16][510][440]
{
  __shared__ float hs[16 * 772];     // chunked [s][b][48], stride 772
  __shared__ float prevs[16 * 177];  // chunked [s][b][11], stride 177
  __shared__ float zl[16 * 17];      // [row][b]
  __shared__ float embS[10];
  const int tid = threadIdx.x;
  const int s = tid & 15;            // k-chunk
  const int r = tid >> 4;            // gate-row (dots) / batch (staging)
  const int uB = blockIdx.x * 4;
  const int j = (r >> 2) * 768 + uB + (r & 3);

  // ---- one-time register weight load ----
  float wx[48], w0[48], w1[48], w2[48], wp[11], pwr[48];
  {
    const float* p = wih0 + (size_t)j * 944 + 48 * s;
#pragma unroll
    for (int i = 0; i < 48; i += 4) {
      float4 v = *(const float4*)(p + i);
      wx[i] = v.x; wx[i+1] = v.y; wx[i+2] = v.z; wx[i+3] = v.w;
    }
    p = whh0 + (size_t)j * 768 + 48 * s;
#pragma unroll
    for (int i = 0; i < 48; i += 4) {
      float4 v = *(const float4*)(p + i);
      w0[i] = v.x; w0[i+1] = v.y; w0[i+2] = v.z; w0[i+3] = v.w;
    }
    p = wih1 + (size_t)j * 768 + 48 * s;
#pragma unroll
    for (int i = 0; i < 48; i += 4) {
      float4 v = *(const float4*)(p + i);
      w1[i] = v.x; w1[i+1] = v.y; w1[i+2] = v.z; w1[i+3] = v.w;
    }
    p = whh1 + (size_t)j * 768 + 48 * s;
#pragma unroll
    for (int i = 0; i < 48; i += 4) {
      float4 v = *(const float4*)(p + i);
      w2[i] = v.x; w2[i+1] = v.y; w2[i+2] = v.z; w2[i+3] = v.w;
    }
    const float* pp = wih0 + (size_t)j * 944 + 768 + 11 * s;
#pragma unroll
    for (int i = 0; i < 11; ++i) wp[i] = pp[i];
  }
  const bool pv = (blockIdx.x < 88) && (r < 5);
  const int prow = blockIdx.x * 5 + r;
  float pbv = 0.f;
  if (pv) {
    const float* p = pw + (size_t)prow * 768 + 48 * s;
#pragma unroll
    for (int i = 0; i < 48; i += 4) {
      float4 v = *(const float4*)(p + i);
      pwr[i] = v.x; pwr[i+1] = v.y; pwr[i+2] = v.z; pwr[i+3] = v.w;
    }
    pbv = pb[prow];
  } else {
#pragma unroll
    for (int i = 0; i < 48; ++i) pwr[i] = 0.f;
  }
  // cell-thread constants (tid<64: ul = tid>>4, b = tid&15)
  float bl1[4], bl2[4], c1 = 0.f, c2 = 0.f;
  if (tid < 64) {
    int ul = tid >> 4;
#pragma unroll
    for (int g = 0; g < 4; ++g) {
      int jj = g * 768 + uB + ul;
      bl1[g] = bih0[jj] + bhh0[jj];
      bl2[g] = bih1[jj] + bhh1[jj];
    }
  }
  if (tid < 10) embS[tid] = emb[tid];

  unsigned nb = 0;
  const unsigned NG = gridDim.x;

  for (int t = 0; t < 510; ++t) {
    const int wbuf = t & 1, rbuf = wbuf ^ 1;
    // ============ PH1a: stage x(t), x-dot ============
    {
      const float* xr = aco + ((size_t)r * 510 + t) * 768 + 48 * s;
      float* dst = hs + s * 772 + r * 48;
#pragma unroll
      for (int i = 0; i < 48; i += 4) *(float4*)(dst + i) = *(const float4*)(xr + i);
    }
    __syncthreads();
    for (int b = 0; b < 16; ++b) {
      float p; CDOT48(wx, hs + s * 772 + b * 48, p);
      p = red16(p);
      if (s == 0) zl[r * 17 + b] = p;
    }
    __syncthreads();
    // ============ PH1b: stage h1(t-1) + prevs, recurrent dot ============
    STAGE_H(h1g + rbuf * 12288);
    if (t == 0) {
      float* pd = prevs + s * 177 + r * 11;
#pragma unroll
      for (int i = 0; i < 11; ++i) pd[i] = 0.f;
    } else {
      const float* pg = prevp + r * 176 + 11 * s;
      float* pd = prevs + s * 177 + r * 11;
#pragma unroll
      for (int i = 0; i < 11; ++i) pd[i] = pg[i];
    }
    __syncthreads();
    for (int b = 0; b < 16; ++b) {
      float p; CDOT48(w0, hs + s * 772 + b * 48, p);
      const float* pvv = prevs + s * 177 + b * 11;
#pragma unroll
      for (int i = 0; i < 11; ++i) p = fmaf(wp[i], pvv[i], p);
      p = red16(p);
      if (s == 0) zl[r * 17 + b] += p;
    }
    __syncthreads();
    if (tid < 64) {
      int ul = tid >> 4, bb = tid & 15;
      float zi = zl[(0 * 4 + ul) * 17 + bb] + bl1[0];
      float zf = zl[(1 * 4 + ul) * 17 + bb] + bl1[1];
      float zg = zl[(2 * 4 + ul) * 17 + bb] + bl1[2];
      float zo = zl[(3 * 4 + ul) * 17 + bb] + bl1[3];
      c1 = sigf(zf) * c1 + sigf(zi) * tanhf(zg);
      h1g[wbuf * 12288 + bb * 768 + uB + ul] = sigf(zo) * tanhf(c1);
    }
    ++nb; gbar(bar, nb, NG);
    // ============ PH2: h2 cell ============
    STAGE_H(h1g + wbuf * 12288);
    __syncthreads();
    for (int b = 0; b < 16; ++b) {
      float p; CDOT48(w1, hs + s * 772 + b * 48, p);
      p = red16(p);
      if (s == 0) zl[r * 17 + b] = p;
    }
    __syncthreads();
    STAGE_H(h2g + rbuf * 12288);
    __syncthreads();
    for (int b = 0; b < 16; ++b) {
      float p; CDOT48(w2, hs + s * 772 + b * 48, p);
      p = red16(p);
      if (s == 0) zl[r * 17 + b] += p;
    }
    __syncthreads();
    if (tid < 64) {
      int ul = tid >> 4, bb = tid & 15;
      float zi = zl[(0 * 4 + ul) * 17 + bb] + bl2[0];
      float zf = zl[(1 * 4 + ul) * 17 + bb] + bl2[1];
      float zg = zl[(2 * 4 + ul) * 17 + bb] + bl2[2];
      float zo = zl[(3 * 4 + ul) * 17 + bb] + bl2[3];
      c2 = sigf(zf) * c2 + sigf(zi) * tanhf(zg);
      h2g[wbuf * 12288 + bb * 768 + uB + ul] = sigf(zo) * tanhf(c2);
    }
    ++nb; gbar(bar, nb, NG);
    // ============ PH3: projection + argmax (blocks < 88, pitch each) ====
    if (blockIdx.x < 88) {
      STAGE_H(h2g + wbuf * 12288);
      __syncthreads();
      for (int b = 0; b < 16; ++b) {
        float p; CDOT48(pwr, hs + s * 772 + b * 48, p);
        p = red16(p);
        if (pv && s == 0) {
          float lg = p + pbv;
          out[((size_t)b * 510 + t) * 440 + prow] = lg;
          zl[r * 17 + b] = lg;
        }
      }
      __syncthreads();
      if (tid < 16) {
        float best = zl[0 * 17 + tid]; int bi = 0;
#pragma unroll
        for (int c = 1; c < 5; ++c) {
          float v = zl[c * 17 + tid];
          if (v > best) { best = v; bi = c; }
        }
        *(float2*)(prevp + tid * 176 + 2 * blockIdx.x) =
            make_float2(embS[bi * 2], embS[bi * 2 + 1]);
      }
    }
    ++nb; gbar(bar, nb, NG);
  }
}

// ---------------------------------------------------------------------------
extern "C" void kernel_launch(void* const* d_in, const int* in_sizes, int n_in,
                              void* d_out, int out_size, void* d_ws, size_t ws_size,
                              hipStream_t stream) {
  (void)in_sizes; (void)n_in; (void)out_size;
  const float* mel  = (const float*)d_in[0];
  const float* c1w  = (const float*)d_in[1];
  const float* c1b  = (const float*)d_in[2];
  const float* c2w  = (const float*)d_in[3];
  const float* c2b  = (const float*)d_in[4];
  const float* c3w  = (const float*)d_in[5];
  const float* c3b  = (const float*)d_in[6];
  const float* bn1g = (const float*)d_in[7];
  const float* bn1b = (const float*)d_in[8];
  const float* bn1m = (const float*)d_in[9];
  const float* bn1v = (const float*)d_in[10];
  const float* bn2g = (const float*)d_in[11];
  const float* bn2b = (const float*)d_in[12];
  const float* bn2m = (const float*)d_in[13];
  const float* bn2v = (const float*)d_in[14];
  const float* bn3g = (const float*)d_in[15];
  const float* bn3b = (const float*)d_in[16];
  const float* bn3m = (const float*)d_in[17];
  const float* bn3v = (const float*)d_in[18];
  const float* fcw  = (const float*)d_in[19];
  const float* fcb  = (const float*)d_in[20];
  const float* wih0 = (const float*)d_in[21];
  const float* whh0 = (const float*)d_in[22];
  const float* bih0 = (const float*)d_in[23];
  const float* bhh0 = (const float*)d_in[24];
  const float* wih1 = (const float*)d_in[25];
  const float* whh1 = (const float*)d_in[26];
  const float* bih1 = (const float*)d_in[27];
  const float* bhh1 = (const float*)d_in[28];
  const float* pw   = (const float*)d_in[29];
  const float* pb   = (const float*)d_in[30];
  const float* emb  = (const float*)d_in[31];

  float* ws = (float*)d_ws;
  float* outp = (float*)d_out;

  const size_t ST_FL = 24576ull + 24576ull + 2816ull;  // h1g + h2g + prevp
  int CB = 1;
  for (int cb = 4; cb >= 1; cb >>= 1) {
    size_t need = (ACO_FL + (size_t)cb * 48 * 512 * 114 + (size_t)cb * 510 * 5472
                   + ST_FL) * 4 + 1024;
    if (ws_size >= need) { CB = cb; break; }
  }
  const int nchunks = 16 / CB;
  const size_t A_FL  = (size_t)CB * 48 * 512 * 114;
  const size_t BF_FL = (size_t)CB * 510 * 5472;

  float* aco = ws;
  float* Ac  = ws + ACO_FL;
  float* Bfc = Ac + A_FL;
  float* h1g = Bfc + BF_FL;
  float* h2g = h1g + 24576;
  float* prevp = h2g + 24576;
  unsigned* bar = (unsigned*)(prevp + 2816);

  for (int ch = 0; ch < nchunks; ++ch) {
    int b0 = ch * CB;
    hipLaunchKernelGGL(conv12_kernel, dim3(CB * 512), dim3(256), 0, stream,
                       mel, c1w, c1b, bn1g, bn1b, bn1m, bn1v,
                       c2w, c2b, bn2g, bn2b, bn2m, bn2v, Ac, b0);
    hipLaunchKernelGGL(conv3_kernel, dim3(CB * 510), dim3(256), 0, stream,
                       Ac, c3w, c3b, bn3g, bn3b, bn3m, bn3v, Bfc);
    int M = CB * 510;
    hipLaunchKernelGGL(gemm_nt, dim3((M + 63) / 64, 12), dim3(256), 0, stream,
                       Bfc, fcw, fcb, aco + (size_t)b0 * 510 * 768,
                       M, 768, 5472, 5472, 5472, 768);
  }
  hipLaunchKernelGGL(init_state, dim3(96), dim3(256), 0, stream, h1g, h2g, bar);

  {
    void* args[] = {
      (void*)&aco, (void*)&whh0, (void*)&wih0, (void*)&wih1, (void*)&whh1,
      (void*)&bih0, (void*)&bhh0, (void*)&bih1, (void*)&bhh1,
      (void*)&pw, (void*)&pb, (void*)&emb,
      (void*)&h1g, (void*)&h2g, (void*)&prevp, (void*)&bar, (void*)&outp
    };
    hipError_t e = hipLaunchCooperativeKernel((const void*)lstm_kernel,
                                              dim3(192), dim3(256), args, 0, stream);
    if (e != hipSuccess) {
      (void)hipGetLastError();
      hipLaunchKernelGGL(lstm_kernel, dim3(192), dim3(256), 0, stream,
                         aco, whh0, wih0, wih1, whh1, bih0, bhh0, bih1, bhh1,
                         pw, pb, emb, h1g, h2g, prevp, bar, outp);
    }
  }
}